// Round 3
// baseline (20168.944 us; speedup 1.0000x reference)
//
#include <hip/hip_runtime.h>
#include <math.h>

// Problem constants (from reference)
#define B_ 32
#define N_ 16384
#define K_ 21
#define C_ 64
#define M_ (N_ - K_ + 1)   // 16364
#define T_ 30
// L = 10.0, LAM = 0.1  ->  1/L = 0.1, LAM/L = 0.01

#define TAF  216   // x outputs per block (64 lanes * 4 - 40 halo)
#define RESW 236   // res values per block (TAF + 20)
#define NT   256   // 4 waves; wave w owns channels [16w, 16w+16)

// One block: batch b, position tile [r0, r0+TAF), all 64 channels.
// Lane l holds x_tmp[w0..w0+3], w0 = r0-20+4l, per channel (registers).
// res windows built with __shfl (no LDS). Cross-wave residual reduction
// through tiny rp/rs LDS. Phase 3 reads res windows from rs (stride-16 b128).
__global__ __launch_bounds__(NT, 4) void fused_step_kernel(
    const float* __restrict__ Xc, const float* __restrict__ Xo,
    float* __restrict__ Xw, const float* __restrict__ y,
    const float* __restrict__ Hg, const float beta, const int first)
{
  __shared__ float rp[4][240];   // per-wave convT partials
  __shared__ float rs[240];      // final residual row

  const int tid = threadIdx.x;
  const int wv  = tid >> 6;
  const int l   = tid & 63;
  const int b   = blockIdx.y;
  const int r0  = blockIdx.x * TAF;
  const int w0  = r0 - 20 + 4 * l;

  float xt[16][4];               // x_tmp windows, 16 channels (64 VGPR)

  if (!first) {
    const bool has_o = (beta != 0.f);
    const bool fast  = (w0 >= 0) && (w0 + 3 < M_);
    float p0 = 0.f, p1 = 0.f, p2 = 0.f, p3 = 0.f;

    #pragma unroll
    for (int cl = 0; cl < 16; ++cl) {
      const int c = __builtin_amdgcn_readfirstlane(wv * 16 + cl);
      const float* pc = Xc + ((size_t)b * C_ + c) * M_;
      const float* po = Xo + ((size_t)b * C_ + c) * M_;
      float a0, a1, a2, a3;
      if (fast) {
        const float4 vc = *(const float4*)(pc + w0);
        a0 = vc.x; a1 = vc.y; a2 = vc.z; a3 = vc.w;
        if (has_o) {
          const float4 vo = *(const float4*)(po + w0);
          a0 = fmaf(beta, a0 - vo.x, a0);
          a1 = fmaf(beta, a1 - vo.y, a1);
          a2 = fmaf(beta, a2 - vo.z, a2);
          a3 = fmaf(beta, a3 - vo.w, a3);
        }
      } else {
        float t[4];
        #pragma unroll
        for (int e = 0; e < 4; ++e) {
          const int ge = w0 + e;
          const bool ok = (ge >= 0) && (ge < M_);
          const float xcv = ok ? pc[ge] : 0.f;
          const float xov = (ok && has_o) ? po[ge] : 0.f;
          t[e] = fmaf(beta, xcv - xov, xcv);
        }
        a0 = t[0]; a1 = t[1]; a2 = t[2]; a3 = t[3];
      }
      xt[cl][0] = a0; xt[cl][1] = a1; xt[cl][2] = a2; xt[cl][3] = a3;

      // 24-wide window via cross-lane shuffles (lanes l+1..l+5)
      float w24[24];
      w24[0] = a0; w24[1] = a1; w24[2] = a2; w24[3] = a3;
      #pragma unroll
      for (int i = 1; i <= 5; ++i) {
        w24[4*i+0] = __shfl(a0, l + i);
        w24[4*i+1] = __shfl(a1, l + i);
        w24[4*i+2] = __shfl(a2, l + i);
        w24[4*i+3] = __shfl(a3, l + i);
      }

      float h[21];
      #pragma unroll
      for (int j = 0; j < K_; ++j) h[j] = Hg[c * K_ + j];  // uniform -> s_load

      // convT partial: res_conv[n=r0+4l+e] += sum_j x_tmp[n-j] h[j]
      #pragma unroll
      for (int u = 0; u <= 20; ++u) {
        const float hv = h[20 - u];
        p0 = fmaf(w24[u],     hv, p0);
        p1 = fmaf(w24[u + 1], hv, p1);
        p2 = fmaf(w24[u + 2], hv, p2);
        p3 = fmaf(w24[u + 3], hv, p3);
      }
    }
    if (l < 59) *(float4*)&rp[wv][4 * l] = make_float4(p0, p1, p2, p3);
  } else {
    #pragma unroll
    for (int cl = 0; cl < 16; ++cl) {
      xt[cl][0] = 0.f; xt[cl][1] = 0.f; xt[cl][2] = 0.f; xt[cl][3] = 0.f;
    }
  }
  __syncthreads();

  // finalize residual: rs[i] = y[r0+i] - sum_waves rp  (0 outside [0,N))
  if (tid < 240) {
    float r = 0.f;
    const int n = r0 + tid;
    if (tid < RESW && n < N_) {
      r = y[(size_t)b * N_ + n];
      if (!first)
        r -= rp[0][tid] + rp[1][tid] + rp[2][tid] + rp[3][tid];
    }
    rs[tid] = r;
  }
  __syncthreads();

  // gradient step + shrink: outputs at this lane's own window base w0
  if (l >= 5 && l < 59 && w0 < M_) {
    float wr[24];
    #pragma unroll
    for (int k = 0; k < 6; ++k)
      *(float4*)&wr[4 * k] = *(const float4*)&rs[4 * (l - 5) + 4 * k];
    #pragma unroll
    for (int cl = 0; cl < 16; ++cl) {
      const int c = __builtin_amdgcn_readfirstlane(wv * 16 + cl);
      float h[21];
      #pragma unroll
      for (int j = 0; j < K_; ++j) h[j] = Hg[c * K_ + j];
      float g0 = 0.f, g1 = 0.f, g2 = 0.f, g3 = 0.f;
      #pragma unroll
      for (int u = 0; u <= 20; ++u) {
        const float hv = h[u];
        g0 = fmaf(wr[u],     hv, g0);
        g1 = fmaf(wr[u + 1], hv, g1);
        g2 = fmaf(wr[u + 2], hv, g2);
        g3 = fmaf(wr[u + 3], hv, g3);
      }
      float o0 = fmaf(g0, 0.1f, xt[cl][0]) - 0.01f; o0 = o0 > 0.f ? o0 : 0.f;
      float o1 = fmaf(g1, 0.1f, xt[cl][1]) - 0.01f; o1 = o1 > 0.f ? o1 : 0.f;
      float o2 = fmaf(g2, 0.1f, xt[cl][2]) - 0.01f; o2 = o2 > 0.f ? o2 : 0.f;
      float o3 = fmaf(g3, 0.1f, xt[cl][3]) - 0.01f; o3 = o3 > 0.f ? o3 : 0.f;
      *(float4*)(Xw + ((size_t)b * C_ + c) * M_ + w0) =
          make_float4(o0, o1, o2, o3);
    }
  }
}

// y_hat[n] = sum_c sum_j x[c][n-j] * H[c][j]   (same machinery, no update)
__global__ __launch_bounds__(NT, 4) void yhat_kernel(
    const float* __restrict__ X, const float* __restrict__ Hg,
    float* __restrict__ out)
{
  __shared__ float rp[4][240];

  const int tid = threadIdx.x;
  const int wv  = tid >> 6;
  const int l   = tid & 63;
  const int b   = blockIdx.y;
  const int r0  = blockIdx.x * RESW;   // 236 y_hat values per block
  const int w0  = r0 - 20 + 4 * l;

  const bool fast = (w0 >= 0) && (w0 + 3 < M_);
  float p0 = 0.f, p1 = 0.f, p2 = 0.f, p3 = 0.f;

  #pragma unroll
  for (int cl = 0; cl < 16; ++cl) {
    const int c = __builtin_amdgcn_readfirstlane(wv * 16 + cl);
    const float* pc = X + ((size_t)b * C_ + c) * M_;
    float a0, a1, a2, a3;
    if (fast) {
      const float4 vc = *(const float4*)(pc + w0);
      a0 = vc.x; a1 = vc.y; a2 = vc.z; a3 = vc.w;
    } else {
      float t[4];
      #pragma unroll
      for (int e = 0; e < 4; ++e) {
        const int ge = w0 + e;
        t[e] = (ge >= 0 && ge < M_) ? pc[ge] : 0.f;
      }
      a0 = t[0]; a1 = t[1]; a2 = t[2]; a3 = t[3];
    }
    float w24[24];
    w24[0] = a0; w24[1] = a1; w24[2] = a2; w24[3] = a3;
    #pragma unroll
    for (int i = 1; i <= 5; ++i) {
      w24[4*i+0] = __shfl(a0, l + i);
      w24[4*i+1] = __shfl(a1, l + i);
      w24[4*i+2] = __shfl(a2, l + i);
      w24[4*i+3] = __shfl(a3, l + i);
    }
    float h[21];
    #pragma unroll
    for (int j = 0; j < K_; ++j) h[j] = Hg[c * K_ + j];
    #pragma unroll
    for (int u = 0; u <= 20; ++u) {
      const float hv = h[20 - u];
      p0 = fmaf(w24[u],     hv, p0);
      p1 = fmaf(w24[u + 1], hv, p1);
      p2 = fmaf(w24[u + 2], hv, p2);
      p3 = fmaf(w24[u + 3], hv, p3);
    }
  }
  if (l < 59) *(float4*)&rp[wv][4 * l] = make_float4(p0, p1, p2, p3);
  __syncthreads();

  if (tid < RESW) {
    const int n = r0 + tid;
    if (n < N_)
      out[(size_t)b * N_ + n] =
          rp[0][tid] + rp[1][tid] + rp[2][tid] + rp[3][tid];
  }
}

extern "C" void kernel_launch(void* const* d_in, const int* in_sizes, int n_in,
                              void* d_out, int out_size, void* d_ws, size_t ws_size,
                              hipStream_t stream)
{
  const float* y = (const float*)d_in[0];   // [B,1,N] fp32
  const float* H = (const float*)d_in[1];   // [C,1,K] fp32
  float* out  = (float*)d_out;
  float* outy = out;                         // [B,N] y_hat region
  float* outx = out + (size_t)B_ * N_;       // [B,C,M] x region

  const size_t SZ = (size_t)B_ * C_ * M_;    // floats per x buffer

  // FISTA momentum scalars: betas[t] = (s_t - 1)/s_{t+1}, s_0 = 1 (betas[0]=0)
  float betas[T_];
  double s = 1.0;
  for (int t = 0; t < T_; ++t) {
    const double sn = (1.0 + sqrt(1.0 + 4.0 * s * s)) * 0.5;
    betas[t] = (float)((s - 1.0) / sn);
    s = sn;
  }

  // 3 rotating x buffers; rotation lands x_30 in outx at t=29.
  float* P[3] = { (float*)d_ws, (float*)d_ws + SZ, outx };
  const dim3 blk(NT);
  const dim3 gF((M_ + TAF - 1) / TAF, B_);   // 76 x 32
  for (int t = 0; t < T_; ++t) {
    const float* Xc = P[(t + 2) % 3];        // x_t      (unused when t==0)
    const float* Xo = P[(t + 1) % 3];        // x_{t-1}  (unused when beta==0)
    float*       Xw = P[t % 3];              // x_{t+1}
    const float beta = (t >= 1) ? betas[t - 1] : 0.f;
    fused_step_kernel<<<gF, blk, 0, stream>>>(Xc, Xo, Xw, y, H, beta, t == 0);
  }
  const dim3 gY((N_ + RESW - 1) / RESW, B_); // 70 x 32
  yhat_kernel<<<gY, blk, 0, stream>>>(outx, H, outy);
}